// Round 5
// baseline (11349.458 us; speedup 1.0000x reference)
//
#include <hip/hip_runtime.h>

// ---------------------------------------------------------------------------
// EdgeTransition — Round 5: pure fp32 VALU bisect kernel (NO MFMA, no packing).
// h = [edge | nb_i | nb_j] (384); t = relu(h@W0+b0); t = relu(t@W1+b1);
// out = LN((t+h)@Wf+bf)
// Block = 16 rows x 256 threads; thread (m = t>>4, ct = t&15) computes row m,
// cols [ct*24, ct*24+24) for trunk GEMMs and cols [ct*8, ct*8+8) for final.
// LDS: A (h / t1+h), B (t0); LN entirely in registers via shfl.
// Goal: decisive structural-vs-MFMA bisect + first green baseline.
// ---------------------------------------------------------------------------

#define ROWS 16
#define PF 388   // fp32 LDS pitch (384 + 4) — breaks bank alignment across rows

// ---------------------------------------------------------------------------
// nb[i][c] = fp32( node[i,:256] @ w_init[:,c] + b_init[c] )   (512 x 128)
// ---------------------------------------------------------------------------
__global__ void node_proj(const float* __restrict__ node,
                          const float* __restrict__ w,
                          const float* __restrict__ b,
                          float* __restrict__ nb) {
  __shared__ float sn[256];
  int i = blockIdx.x;
  int t = threadIdx.x;  // 128 threads
  sn[t] = node[i * 256 + t];
  sn[t + 128] = node[i * 256 + t + 128];
  __syncthreads();
  float acc = b[t];
  for (int k = 0; k < 256; k++) acc += sn[k] * w[k * 128 + t];
  nb[i * 128 + t] = acc;
}

#define FMA4(base, v)                                                         \
  acc[base + 0] += hk * v.x; acc[base + 1] += hk * v.y;                       \
  acc[base + 2] += hk * v.z; acc[base + 3] += hk * v.w;

__global__ __launch_bounds__(256, 3) void edge_fp32(
    const float* __restrict__ edge, const float* __restrict__ nbf,
    const float* __restrict__ w0, const float* __restrict__ b0,
    const float* __restrict__ w1, const float* __restrict__ b1,
    const float* __restrict__ wf, const float* __restrict__ bfin,
    const float* __restrict__ lng, const float* __restrict__ lnb,
    float* __restrict__ out) {
  __shared__ __align__(16) float A[ROWS * PF];   // h, then t1+h
  __shared__ __align__(16) float Bt[ROWS * PF];  // t0

  const int t = threadIdx.x;
  const int m = t >> 4, ct = t & 15;
  const int r0 = blockIdx.x * ROWS;
  const int i_node = r0 >> 9, j0 = r0 & 511;
  const size_t erow = ((size_t)r0 + m) * 128;  // row (i, j0+m) base in edge/out

  // ---- stage h = [edge | nb_i | nb_j] into A ----
  {
    const float* ep = edge + erow + ct * 8;
    *(float4*)(A + m * PF + ct * 8)     = *(const float4*)ep;
    *(float4*)(A + m * PF + ct * 8 + 4) = *(const float4*)(ep + 4);
    const float* bi = nbf + i_node * 128 + ct * 8;
    *(float4*)(A + m * PF + 128 + ct * 8)     = *(const float4*)bi;
    *(float4*)(A + m * PF + 128 + ct * 8 + 4) = *(const float4*)(bi + 4);
    const float* bj = nbf + (size_t)(j0 + m) * 128 + ct * 8;
    *(float4*)(A + m * PF + 256 + ct * 8)     = *(const float4*)bj;
    *(float4*)(A + m * PF + 256 + ct * 8 + 4) = *(const float4*)(bj + 4);
  }
  __syncthreads();

  // ---- trunk: layer0 A->Bt (w0), layer1 Bt->A (w1, + residual h) ----
  for (int layer = 0; layer < 2; layer++) {
    const float* src = layer ? Bt : A;
    float* dst = layer ? A : Bt;
    const float* w = layer ? w1 : w0;
    const float* bias = layer ? b1 : b0;

    float acc[24];
#pragma unroll
    for (int c = 0; c < 24; c++) acc[c] = 0.0f;

    const float* srow = src + m * PF;
#pragma unroll 2
    for (int k = 0; k < 384; k++) {
      float hk = srow[k];
      const float4* w4 = (const float4*)(w + k * 384 + ct * 24);
      float4 a0 = w4[0], a1 = w4[1], a2 = w4[2];
      float4 a3 = w4[3], a4 = w4[4], a5 = w4[5];
      FMA4(0, a0) FMA4(4, a1) FMA4(8, a2)
      FMA4(12, a3) FMA4(16, a4) FMA4(20, a5)
    }

    // epilogue: bias + ReLU (+ residual h on layer 1), write to dst
    float* drow = dst + m * PF + ct * 24;
    const float* brow = bias + ct * 24;
#pragma unroll
    for (int c = 0; c < 24; c++) {
      float v = fmaxf(acc[c] + brow[c], 0.0f);
      if (layer == 1) {
        int col = ct * 24 + c;
        float hv = (col < 128) ? edge[erow + col]
                 : (col < 256) ? nbf[i_node * 128 + (col - 128)]
                               : nbf[(size_t)(j0 + m) * 128 + (col - 256)];
        v += hv;
      }
      drow[c] = v;
    }
    __syncthreads();
  }

  // ---- final Linear 384x128 + bias (A -> registers), then LN + store ----
  {
    float acc[8];
#pragma unroll
    for (int c = 0; c < 8; c++) acc[c] = 0.0f;
    const float* srow = A + m * PF;
#pragma unroll 2
    for (int k = 0; k < 384; k++) {
      float hk = srow[k];
      const float4* w4 = (const float4*)(wf + k * 128 + ct * 8);
      float4 a0 = w4[0], a1 = w4[1];
      FMA4(0, a0) FMA4(4, a1)
    }
#pragma unroll
    for (int c = 0; c < 8; c++) acc[c] += bfin[ct * 8 + c];

    // LayerNorm over 128 cols: reduce across the 16 ct-lanes of row m
    float s = 0.0f, q = 0.0f;
#pragma unroll
    for (int c = 0; c < 8; c++) { s += acc[c]; q += acc[c] * acc[c]; }
#pragma unroll
    for (int off = 1; off <= 8; off <<= 1) {
      s += __shfl_xor(s, off);
      q += __shfl_xor(q, off);
    }
    float mu = s * (1.0f / 128.0f);
    float var = q * (1.0f / 128.0f) - mu * mu;
    float rstd = rsqrtf(var + 1e-5f);

    float4 g0 = *(const float4*)(lng + ct * 8);
    float4 g1 = *(const float4*)(lng + ct * 8 + 4);
    float4 bb0 = *(const float4*)(lnb + ct * 8);
    float4 bb1 = *(const float4*)(lnb + ct * 8 + 4);
    float4 o0, o1;
    o0.x = (acc[0] - mu) * rstd * g0.x + bb0.x;
    o0.y = (acc[1] - mu) * rstd * g0.y + bb0.y;
    o0.z = (acc[2] - mu) * rstd * g0.z + bb0.z;
    o0.w = (acc[3] - mu) * rstd * g0.w + bb0.w;
    o1.x = (acc[4] - mu) * rstd * g1.x + bb1.x;
    o1.y = (acc[5] - mu) * rstd * g1.y + bb1.y;
    o1.z = (acc[6] - mu) * rstd * g1.z + bb1.z;
    o1.w = (acc[7] - mu) * rstd * g1.w + bb1.w;
    float* op = out + erow + ct * 8;
    *(float4*)op = o0;
    *(float4*)(op + 4) = o1;
  }
}

extern "C" void kernel_launch(void* const* d_in, const int* in_sizes, int n_in,
                              void* d_out, int out_size, void* d_ws, size_t ws_size,
                              hipStream_t stream) {
  const float* node   = (const float*)d_in[0];
  const float* edge   = (const float*)d_in[1];
  const float* w_init = (const float*)d_in[2];
  const float* b_init = (const float*)d_in[3];
  const float* w_t0   = (const float*)d_in[4];
  const float* b_t0   = (const float*)d_in[5];
  const float* w_t1   = (const float*)d_in[6];
  const float* b_t1   = (const float*)d_in[7];
  const float* w_fin  = (const float*)d_in[8];
  const float* b_fin  = (const float*)d_in[9];
  const float* ln_g   = (const float*)d_in[10];
  const float* ln_b   = (const float*)d_in[11];
  float* out = (float*)d_out;

  float* nb = (float*)d_ws;  // 512*128*4 = 262144 B — only ws use this round

  node_proj<<<512, 128, 0, stream>>>(node, w_init, b_init, nb);
  edge_fp32<<<16384, 256, 0, stream>>>(edge, nb, w_t0, b_t0, w_t1, b_t1,
                                       w_fin, b_fin, ln_g, ln_b, out);
}